// Round 19
// baseline (509.095 us; speedup 1.0000x reference)
//
#include <hip/hip_runtime.h>
#include <math.h>

// StreamingTransformerLayer on MI355X (gfx950).  Round 19.
// B=8 T=256 C=2048 H=16 Dh=128 CAP=2048 FF=8192, offset read on-device.
// R19: consolidate to best-measured config (R15 = 444.8us):
//  - GEMM: 2-phase __syncthreads loop + T2 source-swizzle + XCD band map
//  - attn: single-dispatch 512-block QBLK=64 kernel (split-S dropped: R18 showed
//    occupancy pinned at ~20% regardless of grid; combine kernel was pure cost)
//  + T13 defer-max (THR=8) in attn softmax: skip accO rescale unless the wave's
//    chunk max actually grows (R4-verified __any pattern; catalog +5% on attn).

typedef __bf16 bf16_t;
typedef __bf16 bf16x8 __attribute__((ext_vector_type(8)));
typedef float  f32x4  __attribute__((ext_vector_type(4)));

#define MFMA(a, b, c) __builtin_amdgcn_mfma_f32_16x16x32_bf16((a), (b), (c), 0, 0, 0)

static __device__ __forceinline__ bf16x8 cvt8(const float* __restrict__ src) {
    f32x4 f0 = *(const f32x4*)src;
    f32x4 f1 = *(const f32x4*)(src + 4);
    bf16x8 v;
    v[0] = (bf16_t)f0[0]; v[1] = (bf16_t)f0[1]; v[2] = (bf16_t)f0[2]; v[3] = (bf16_t)f0[3];
    v[4] = (bf16_t)f1[0]; v[5] = (bf16_t)f1[1]; v[6] = (bf16_t)f1[2]; v[7] = (bf16_t)f1[3];
    return v;
}

// async global->LDS, 16B per lane; lds base must be wave-uniform
static __device__ __forceinline__ void gload16(const bf16_t* g, bf16_t* lds) {
    __builtin_amdgcn_global_load_lds(
        (const __attribute__((address_space(1))) void*)g,
        (__attribute__((address_space(3))) void*)lds, 16, 0, 0);
}

// ---------------- weight convert: rows x cols, row stride (f32 -> bf16) ----------------
__global__ __launch_bounds__(256)
void cvt_rows_kernel(const float* __restrict__ src, bf16_t* __restrict__ dst,
                     int cols, int src_stride)
{
    const int row = blockIdx.x;
    const float* s = src + (size_t)row * src_stride;
    bf16_t* d = dst + (size_t)row * cols;
    for (int c = threadIdx.x * 8; c < cols; c += blockDim.x * 8)
        *(bf16x8*)&d[c] = cvt8(&s[c]);
}

// ---------------- RMSNorm: one block per row of 2048 f32, out bf16 ----------------
__global__ __launch_bounds__(256)
void rmsnorm_kernel(const float* __restrict__ x, const float* __restrict__ alpha,
                    bf16_t* __restrict__ out)
{
    const int C = 2048;
    const int row = blockIdx.x;
    const int tid = threadIdx.x;
    const float* xr = x + (size_t)row * C;
    f32x4 a0 = *(const f32x4*)&xr[tid * 8];
    f32x4 a1 = *(const f32x4*)&xr[tid * 8 + 4];
    float ss = a0[0]*a0[0] + a0[1]*a0[1] + a0[2]*a0[2] + a0[3]*a0[3]
             + a1[0]*a1[0] + a1[1]*a1[1] + a1[2]*a1[2] + a1[3]*a1[3];
    #pragma unroll
    for (int d = 32; d >= 1; d >>= 1) ss += __shfl_xor(ss, d);
    __shared__ float red[4];
    const int lane = tid & 63, wid = tid >> 6;
    if (lane == 0) red[wid] = ss;
    __syncthreads();
    const float tot = red[0] + red[1] + red[2] + red[3];
    const float rs = rsqrtf(1e-5f + tot * (1.0f / C));
    f32x4 l0 = *(const f32x4*)&alpha[tid * 8];
    f32x4 l1 = *(const f32x4*)&alpha[tid * 8 + 4];
    bf16x8 o8;
    o8[0] = (bf16_t)(a0[0] * l0[0] * rs); o8[1] = (bf16_t)(a0[1] * l0[1] * rs);
    o8[2] = (bf16_t)(a0[2] * l0[2] * rs); o8[3] = (bf16_t)(a0[3] * l0[3] * rs);
    o8[4] = (bf16_t)(a1[0] * l1[0] * rs); o8[5] = (bf16_t)(a1[1] * l1[1] * rs);
    o8[6] = (bf16_t)(a1[2] * l1[2] * rs); o8[7] = (bf16_t)(a1[3] * l1[3] * rs);
    *(bf16x8*)&out[(size_t)row * C + tid * 8] = o8;
}

// ---------------- GEMM (2-phase + T2 source-swizzle, R15-verified): C = A*B^T ----------
// LDS slot (row, j) holds global chunk j ^ (row&7); read chunk c at slot c^(row&7).
// EPI: 0 f32 | 1 res+acc f32 | 2 gelu bf16 | 3 bf16
template<int EPI, int NSPLIT>
__global__ __launch_bounds__(256)
void gemm_bb(const bf16_t* __restrict__ A, const bf16_t* __restrict__ B,
             float* Cf, bf16_t* Cb, const float* __restrict__ res,
             int M, int N, int K, int lda, int ldb)
{
    __shared__ bf16_t As[2][128 * 64];
    __shared__ bf16_t Bs[2][128 * 64];
    if constexpr (NSPLIT > 1) {
        A  += (size_t)blockIdx.z * K;
        B  += (size_t)blockIdx.z * K;
        Cb += (size_t)blockIdx.z * (size_t)M * N;
    }
    // XCD band mapping (verified: FETCH 266->66 MB). Requires gx % 8 == 0.
    const int gx = gridDim.x;
    const int orig = blockIdx.y * gx + blockIdx.x;
    const int xcd = orig & 7;
    const int i = orig >> 3;
    const int bw = gx >> 3;
    const int m0 = (i / bw) * 128;
    const int n0 = (xcd * bw + (i % bw)) * 128;

    const int tid = threadIdx.x;
    const int lane = tid & 63, wid = tid >> 6;
    const int wr = wid >> 1, wc = wid & 1;
    const int lr = lane & 15, lg = lane >> 4;
    const int srow = lane >> 3;
    const int scol_swz = (((lane & 7) ^ (lane >> 3)) << 3);  // pre-swizzled source chunk
    f32x4 acc[4][4] = {};

    const int nt = K >> 6;
    const bf16_t* Ab = A + (size_t)m0 * lda;
    const bf16_t* Bb = B + (size_t)n0 * ldb;

    #define STAGE(bufi, kt)                                                               \
        _Pragma("unroll")                                                                 \
        for (int it = 0; it < 4; ++it) {                                                  \
            const int r = wid * 32 + it * 8;                                              \
            gload16(&Ab[(size_t)(r + srow) * lda + (kt) + scol_swz], &As[bufi][r * 64]);  \
            gload16(&Bb[(size_t)(r + srow) * ldb + (kt) + scol_swz], &Bs[bufi][r * 64]);  \
        }

    STAGE(0, 0);
    __syncthreads();
    int cur = 0;
    for (int t = 0; t < nt; ++t) {
        if (t + 1 < nt) STAGE(cur ^ 1, (t + 1) << 6);
        __builtin_amdgcn_s_setprio(1);
        #pragma unroll
        for (int kk = 0; kk < 2; ++kk) {
            bf16x8 af[4], bfr[4];
            #pragma unroll
            for (int m = 0; m < 4; ++m)
                af[m] = *(const bf16x8*)&As[cur][(wr * 64 + m * 16 + lr) * 64
                                                 + (((kk * 4 + lg) ^ (lr & 7)) << 3)];
            #pragma unroll
            for (int n = 0; n < 4; ++n)
                bfr[n] = *(const bf16x8*)&Bs[cur][(wc * 64 + n * 16 + lr) * 64
                                                  + (((kk * 4 + lg) ^ (lr & 7)) << 3)];
            #pragma unroll
            for (int m = 0; m < 4; ++m)
                #pragma unroll
                for (int n = 0; n < 4; ++n)
                    acc[m][n] = MFMA(af[m], bfr[n], acc[m][n]);
        }
        __builtin_amdgcn_s_setprio(0);
        __syncthreads();                         // one barrier/K-step, after compute
        cur ^= 1;
    }
    #undef STAGE

    // epilogue; C/D frag: col=lane&15, row=(lane>>4)*4+reg (m89-verified)
    #pragma unroll
    for (int m = 0; m < 4; ++m) {
        #pragma unroll
        for (int n = 0; n < 4; ++n) {
            const int gmb = m0 + wr * 64 + m * 16 + lg * 4;
            const int gn  = n0 + wc * 64 + n * 16 + lr;
            #pragma unroll
            for (int r = 0; r < 4; ++r) {
                const size_t off = (size_t)(gmb + r) * N + gn;
                const float v = acc[m][n][r];
                if (EPI == 0)      Cf[off] = v;
                else if (EPI == 1) Cf[off] = res[off] + v;
                else if (EPI == 2) Cb[off] = (bf16_t)(0.5f * v * (1.0f + erff(v * 0.70710678118654752f)));
                else               Cb[off] = (bf16_t)v;
            }
        }
    }
}

// ---------------- split-K reduce: out[i] = res[i] + sum_z (f32)p[z*n+i] ----------------
template<int Z>
__global__ __launch_bounds__(256)
void reduce_sk_kernel(const bf16_t* __restrict__ p, const float* __restrict__ res,
                      float* __restrict__ out, int n)
{
    for (int i = (blockIdx.x * 256 + threadIdx.x) * 8; i < n; i += gridDim.x * 256 * 8) {
        f32x4 r0 = *(const f32x4*)&res[i];
        f32x4 r1 = *(const f32x4*)&res[i + 4];
        #pragma unroll
        for (int z = 0; z < Z; ++z) {
            bf16x8 v = *(const bf16x8*)&p[(size_t)z * n + i];
            r0[0] += (float)v[0]; r0[1] += (float)v[1]; r0[2] += (float)v[2]; r0[3] += (float)v[3];
            r1[0] += (float)v[4]; r1[1] += (float)v[5]; r1[2] += (float)v[6]; r1[3] += (float)v[7];
        }
        *(f32x4*)&out[i] = r0;
        *(f32x4*)&out[i + 4] = r1;
    }
}

// ---------------- RoPE + split qkv -> q/kn/vn in [B*H][T][Dh] bf16 ----------------
__global__ __launch_bounds__(256)
void rope_split_kernel(const bf16_t* __restrict__ qkv,
                       bf16_t* __restrict__ q, bf16_t* __restrict__ kn,
                       bf16_t* __restrict__ vn, const int* __restrict__ offp)
{
    const int m = blockIdx.x;            // b*T + t
    const int b = m >> 8, t = m & 255;
    const int tid = threadIdx.x;
    const int c = tid * 8;
    const int h = c >> 7, d0 = c & 127;
    const int pos = offp[0] + t;
    bf16x8 qv = *(const bf16x8*)&qkv[(size_t)m * 6144 + c];
    bf16x8 kv = *(const bf16x8*)&qkv[(size_t)m * 6144 + 2048 + c];
    bf16x8 vv = *(const bf16x8*)&qkv[(size_t)m * 6144 + 4096 + c];
    bf16x8 qo, ko;
    #pragma unroll
    for (int p = 0; p < 4; ++p) {
        const int i = (d0 >> 1) + p;
        const float ang = (float)pos * __expf(-(float)i * 0.14391156861538527f); // ln(1e4)/64
        const float sn = sinf(ang), cs = cosf(ang);
        const float q1 = (float)qv[2 * p], q2 = (float)qv[2 * p + 1];
        const float k1 = (float)kv[2 * p], k2 = (float)kv[2 * p + 1];
        qo[2 * p]     = (bf16_t)(q1 * cs - q2 * sn);
        qo[2 * p + 1] = (bf16_t)(q1 * sn + q2 * cs);
        ko[2 * p]     = (bf16_t)(k1 * cs - k2 * sn);
        ko[2 * p + 1] = (bf16_t)(k1 * sn + k2 * cs);
    }
    const size_t oi = (((size_t)(b * 16 + h) * 256) + t) * 128 + d0;
    *(bf16x8*)&q[oi]  = qo;
    *(bf16x8*)&kn[oi] = ko;
    *(bf16x8*)&vn[oi] = vv;
}

// ---------------- Flash attention (R15 + T13 defer-max): block = (b,h) x 64 Q rows ----
// 4 waves x 16 rows. Single-buffered. Vt swizzle:
// elem(d,s)=d*64+(((s>>3)^(d&7)^((d>>3)&7))<<3)+(s&7)
__global__ __launch_bounds__(256)
void attn_kernel(const bf16_t* __restrict__ qh, const bf16_t* __restrict__ kn,
                 const bf16_t* __restrict__ vn, const float* __restrict__ kcache,
                 const float* __restrict__ vcache, bf16_t* __restrict__ outp,
                 const int* __restrict__ offp)
{
    const int T = 256, Dh = 128, CAP = 2048, H = 16;
    const float scale = 0.08838834764831845f;   // 1/sqrt(128)
    __shared__ bf16_t Ks[64][136];      // [s][d], +8 pad (2-way r/w)
    __shared__ bf16_t VtL[128 * 64];    // swizzled [d][s]
    __shared__ bf16_t Pl[4][16][72];    // per-wave P relayout
    const int bh = blockIdx.x;
    const int t0 = blockIdx.y * 64;
    const int b = bh >> 4, h = bh & 15;
    const int offset = offp[0];
    const int Stot = offset + T;        // assumes offset+T <= CAP (holds here)
    const int tid = threadIdx.x, lane = tid & 63, wid = tid >> 6;
    const int lr = lane & 15, lg = lane >> 4;

    bf16x8 qf[4];
    {
        const bf16_t* qbase = qh + ((size_t)bh * T + t0 + wid * 16) * Dh;
        #pragma unroll
        for (int ks = 0; ks < 4; ++ks)
            qf[ks] = *(const bf16x8*)&qbase[lr * Dh + ks * 32 + lg * 8];
    }
    f32x4 accO[8] = {};
    float mrun[4], lrun[4];
    #pragma unroll
    for (int r = 0; r < 4; ++r) { mrun[r] = -3e38f; lrun[r] = 0.0f; }

    int smax = offset + t0 + 64; if (smax > Stot) smax = Stot;
    const int nch = (smax + 63) >> 6;

    for (int ch = 0; ch < nch; ++ch) {
        const int s0 = ch * 64;
        __syncthreads();
        #pragma unroll
        for (int it = 0; it < 4; ++it) {
            const int idx = tid + it * 256;          // 64 rows x 16 col-groups
            const int r = idx >> 4, c8 = idx & 15;
            const int s = s0 + r;
            bf16x8 kv8, vv8;
            if (s < offset) {
                const size_t base = (((size_t)b * H + h) * CAP + s) * Dh + c8 * 8;
                kv8 = cvt8(&kcache[base]);
                vv8 = cvt8(&vcache[base]);
            } else if (s < Stot) {
                const size_t base = ((size_t)bh * T + (s - offset)) * Dh + c8 * 8;
                kv8 = *(const bf16x8*)&kn[base];
                vv8 = *(const bf16x8*)&vn[base];
            } else {
                #pragma unroll
                for (int j = 0; j < 8; ++j) { kv8[j] = (bf16_t)0.0f; vv8[j] = (bf16_t)0.0f; }
            }
            *(bf16x8*)&Ks[r][c8 * 8] = kv8;
            #pragma unroll
            for (int j = 0; j < 8; ++j)
                VtL[(c8 * 8 + j) * 64 + ((((r >> 3) ^ j ^ (c8 & 7))) << 3) + (r & 7)] = vv8[j];
        }
        __syncthreads();

        f32x4 sc[4] = {};
        #pragma unroll
        for (int ks = 0; ks < 4; ++ks) {
            bf16x8 kf[4];
            #pragma unroll
            for (int n = 0; n < 4; ++n)
                kf[n] = *(const bf16x8*)&Ks[n * 16 + lr][ks * 32 + lg * 8];
            #pragma unroll
            for (int n = 0; n < 4; ++n)
                sc[n] = MFMA(qf[ks], kf[n], sc[n]);
        }

        #pragma unroll
        for (int r = 0; r < 4; ++r) {
            const int qpos = offset + t0 + wid * 16 + lg * 4 + r;
            float mx = -3e38f;
            #pragma unroll
            for (int n = 0; n < 4; ++n) {
                const int sabs = s0 + n * 16 + lr;
                float v = sc[n][r] * scale;
                v = (sabs <= qpos && sabs < Stot) ? v : -1e30f;
                sc[n][r] = v;
                mx = fmaxf(mx, v);
            }
            #pragma unroll
            for (int d = 8; d >= 1; d >>= 1) mx = fmaxf(mx, __shfl_xor(mx, d));
            const float mo = mrun[r];
            float mn2 = mo;
            if (__any(mx > mo + 8.0f)) {            // T13: rescale only on real growth
                mn2 = fmaxf(mo, mx);
                const float al = __expf(mo - mn2);
                mrun[r] = mn2;
                lrun[r] *= al;
                #pragma unroll
                for (int df = 0; df < 8; ++df) accO[df][r] *= al;
            }
            float rsum = 0.0f;
            #pragma unroll
            for (int n = 0; n < 4; ++n) {
                const float p = __expf(sc[n][r] - mn2);
                sc[n][r] = p;
                rsum += p;
            }
            #pragma unroll
            for (int d = 8; d >= 1; d >>= 1) rsum += __shfl_xor(rsum, d);
            lrun[r] += rsum;
            #pragma unroll
            for (int n = 0; n < 4; ++n)
                Pl[wid][lg * 4 + r][n * 16 + lr] = (bf16_t)sc[n][r];
        }
        asm volatile("s_waitcnt lgkmcnt(0)" ::: "memory");
        __builtin_amdgcn_sched_barrier(0);

        #pragma unroll
        for (int ks2 = 0; ks2 < 2; ++ks2) {
            const bf16x8 pa = *(const bf16x8*)&Pl[wid][lr][ks2 * 32 + lg * 8];
            #pragma unroll
            for (int df = 0; df < 8; ++df) {
                const int d = df * 16 + lr;
                const bf16x8 vb8 = *(const bf16x8*)
                    &VtL[d * 64 + (((ks2 * 4 + lg) ^ (d & 7) ^ ((d >> 3) & 7)) << 3)];
                accO[df] = MFMA(pa, vb8, accO[df]);
            }
        }
    }

    float rinv[4];
    #pragma unroll
    for (int r = 0; r < 4; ++r) rinv[r] = 1.0f / lrun[r];
    #pragma unroll
    for (int df = 0; df < 8; ++df) {
        #pragma unroll
        for (int r = 0; r < 4; ++r) {
            const int t = t0 + wid * 16 + lg * 4 + r;
            outp[((size_t)b * 256 + t) * 2048 + h * 128 + df * 16 + lr] =
                (bf16_t)(accO[df][r] * rinv[r]);
        }
    }
}

// ---------------- launch ----------------
extern "C" void kernel_launch(void* const* d_in, const int* in_sizes, int n_in,
                              void* d_out, int out_size, void* d_ws, size_t ws_size,
                              hipStream_t stream)
{
    const float* x    = (const float*)d_in[0];
    const float* kc   = (const float*)d_in[1];
    const float* vc   = (const float*)d_in[2];
    const float* wqkv = (const float*)d_in[3];
    const float* wo   = (const float*)d_in[4];
    const float* a1   = (const float*)d_in[5];
    const float* a2   = (const float*)d_in[6];
    const float* w1   = (const float*)d_in[7];
    const float* w2   = (const float*)d_in[8];
    const int*   offp = (const int*)d_in[9];
    float* out = (float*)d_out;

    char* ws = (char*)d_ws;
    // phase A: xn[0,8) wqkv_b[8,32) qkv[32,56)
    // phase B: q[8,16) kn[16,24) vn[24,32) wo_b[32,40) o[40,48) oprt[48,64)
    // phase C (fallback): hbuf[0,8) w1b[8,24) g_h[24,40) w2b[40,56); partials reuse [8,24)
    // phase C (big ws):   hbuf[0,8) w1b[8,40) g[40,72) w2b[72,104) partials[104,136)
    bf16_t* xn     = (bf16_t*)(ws + 0);
    bf16_t* wqkv_b = (bf16_t*)(ws + (8ull  << 20));
    bf16_t* qkv    = (bf16_t*)(ws + (32ull << 20));
    bf16_t* q      = (bf16_t*)(ws + (8ull  << 20));
    bf16_t* kn     = (bf16_t*)(ws + (16ull << 20));
    bf16_t* vn     = (bf16_t*)(ws + (24ull << 20));
    bf16_t* wo_b   = (bf16_t*)(ws + (32ull << 20));
    bf16_t* o      = (bf16_t*)(ws + (40ull << 20));
    bf16_t* oprt   = (bf16_t*)(ws + (48ull << 20));
    bf16_t* hbuf   = (bf16_t*)(ws + 0);
    const bool bigws = ws_size >= (137ull << 20);

    rmsnorm_kernel<<<2048, 256, 0, stream>>>(x, a1, xn);
    cvt_rows_kernel<<<6144, 256, 0, stream>>>(wqkv, wqkv_b, 2048, 2048);
    gemm_bb<3, 1><<<dim3(48, 16), 256, 0, stream>>>(xn, wqkv_b, nullptr, qkv, nullptr,
                                                    2048, 6144, 2048, 2048, 2048);
    rope_split_kernel<<<2048, 256, 0, stream>>>(qkv, q, kn, vn, offp);
    cvt_rows_kernel<<<2048, 256, 0, stream>>>(wo, wo_b, 2048, 2048);
    attn_kernel<<<dim3(128, 4), 256, 0, stream>>>(q, kn, vn, kc, vc, o, offp);
    gemm_bb<3, 2><<<dim3(16, 16, 2), 256, 0, stream>>>(o, wo_b, nullptr, oprt, nullptr,
                                                       2048, 2048, 1024, 2048, 2048);
    reduce_sk_kernel<2><<<2048, 256, 0, stream>>>(oprt, x, out, 2048 * 2048);
    rmsnorm_kernel<<<2048, 256, 0, stream>>>(out, a2, hbuf);

    if (bigws) {
        bf16_t* w1b = (bf16_t*)(ws + (8ull   << 20));
        bf16_t* g   = (bf16_t*)(ws + (40ull  << 20));
        bf16_t* w2b = (bf16_t*)(ws + (72ull  << 20));
        bf16_t* prt = (bf16_t*)(ws + (104ull << 20));
        cvt_rows_kernel<<<8192, 256, 0, stream>>>(w1, w1b, 2048, 2048);
        gemm_bb<2, 1><<<dim3(64, 16), 256, 0, stream>>>(hbuf, w1b, nullptr, g, nullptr,
                                                        2048, 8192, 2048, 2048, 2048);
        cvt_rows_kernel<<<2048, 256, 0, stream>>>(w2, w2b, 8192, 8192);
        gemm_bb<3, 4><<<dim3(16, 16, 4), 256, 0, stream>>>(g, w2b, nullptr, prt, nullptr,
                                                           2048, 2048, 2048, 8192, 8192);
        reduce_sk_kernel<4><<<2048, 256, 0, stream>>>(prt, out, out, 2048 * 2048);
    } else {
        bf16_t* w1b = (bf16_t*)(ws + (8ull  << 20));
        bf16_t* g_h = (bf16_t*)(ws + (24ull << 20));
        bf16_t* w2b = (bf16_t*)(ws + (40ull << 20));
        bf16_t* prt = (bf16_t*)(ws + (8ull  << 20));
        for (int hh = 0; hh < 2; ++hh) {
            cvt_rows_kernel<<<4096, 256, 0, stream>>>(w1 + (size_t)hh * 4096 * 2048, w1b, 2048, 2048);
            gemm_bb<2, 1><<<dim3(32, 16), 256, 0, stream>>>(hbuf, w1b, nullptr, g_h, nullptr,
                                                            2048, 4096, 2048, 2048, 2048);
            cvt_rows_kernel<<<2048, 256, 0, stream>>>(w2 + (size_t)hh * 4096, w2b, 4096, 8192);
            gemm_bb<3, 2><<<dim3(16, 16, 2), 256, 0, stream>>>(g_h, w2b, nullptr, prt, nullptr,
                                                               2048, 2048, 2048, 4096, 4096);
            reduce_sk_kernel<2><<<2048, 256, 0, stream>>>(prt, out, out, 2048 * 2048);
        }
    }
}

// Round 20
// 446.872 us; speedup vs baseline: 1.1392x; 1.1392x over previous
//
#include <hip/hip_runtime.h>
#include <math.h>

// StreamingTransformerLayer on MI355X (gfx950).  Round 20 = exact R15 config
// (best measured: 444.8us). B=8 T=256 C=2048 H=16 Dh=128 CAP=2048 FF=8192.
// GEMM: 2-phase prefetch (__syncthreads after compute) + T2 source-swizzle
//       (SQ_LDS_BANK_CONFLICT 2.5e7 -> ~0 verified) + XCD band map (FETCH
//       266->66MB verified).
// attn: QBLK=64 grid 512, Vt both-sides XOR swizzle (conflicts 2.1e7->7.6e6),
//       plain online softmax (T13 regressed: divergent branch -> VGPR 140,
//       occupancy 20.7->11%, FETCH +70MB; R19 post-mortem).

typedef __bf16 bf16_t;
typedef __bf16 bf16x8 __attribute__((ext_vector_type(8)));
typedef float  f32x4  __attribute__((ext_vector_type(4)));

#define MFMA(a, b, c) __builtin_amdgcn_mfma_f32_16x16x32_bf16((a), (b), (c), 0, 0, 0)

static __device__ __forceinline__ bf16x8 cvt8(const float* __restrict__ src) {
    f32x4 f0 = *(const f32x4*)src;
    f32x4 f1 = *(const f32x4*)(src + 4);
    bf16x8 v;
    v[0] = (bf16_t)f0[0]; v[1] = (bf16_t)f0[1]; v[2] = (bf16_t)f0[2]; v[3] = (bf16_t)f0[3];
    v[4] = (bf16_t)f1[0]; v[5] = (bf16_t)f1[1]; v[6] = (bf16_t)f1[2]; v[7] = (bf16_t)f1[3];
    return v;
}

// async global->LDS, 16B per lane; lds base must be wave-uniform
static __device__ __forceinline__ void gload16(const bf16_t* g, bf16_t* lds) {
    __builtin_amdgcn_global_load_lds(
        (const __attribute__((address_space(1))) void*)g,
        (__attribute__((address_space(3))) void*)lds, 16, 0, 0);
}

// ---------------- weight convert: rows x cols, row stride (f32 -> bf16) ----------------
__global__ __launch_bounds__(256)
void cvt_rows_kernel(const float* __restrict__ src, bf16_t* __restrict__ dst,
                     int cols, int src_stride)
{
    const int row = blockIdx.x;
    const float* s = src + (size_t)row * src_stride;
    bf16_t* d = dst + (size_t)row * cols;
    for (int c = threadIdx.x * 8; c < cols; c += blockDim.x * 8)
        *(bf16x8*)&d[c] = cvt8(&s[c]);
}

// ---------------- RMSNorm: one block per row of 2048 f32, out bf16 ----------------
__global__ __launch_bounds__(256)
void rmsnorm_kernel(const float* __restrict__ x, const float* __restrict__ alpha,
                    bf16_t* __restrict__ out)
{
    const int C = 2048;
    const int row = blockIdx.x;
    const int tid = threadIdx.x;
    const float* xr = x + (size_t)row * C;
    f32x4 a0 = *(const f32x4*)&xr[tid * 8];
    f32x4 a1 = *(const f32x4*)&xr[tid * 8 + 4];
    float ss = a0[0]*a0[0] + a0[1]*a0[1] + a0[2]*a0[2] + a0[3]*a0[3]
             + a1[0]*a1[0] + a1[1]*a1[1] + a1[2]*a1[2] + a1[3]*a1[3];
    #pragma unroll
    for (int d = 32; d >= 1; d >>= 1) ss += __shfl_xor(ss, d);
    __shared__ float red[4];
    const int lane = tid & 63, wid = tid >> 6;
    if (lane == 0) red[wid] = ss;
    __syncthreads();
    const float tot = red[0] + red[1] + red[2] + red[3];
    const float rs = rsqrtf(1e-5f + tot * (1.0f / C));
    f32x4 l0 = *(const f32x4*)&alpha[tid * 8];
    f32x4 l1 = *(const f32x4*)&alpha[tid * 8 + 4];
    bf16x8 o8;
    o8[0] = (bf16_t)(a0[0] * l0[0] * rs); o8[1] = (bf16_t)(a0[1] * l0[1] * rs);
    o8[2] = (bf16_t)(a0[2] * l0[2] * rs); o8[3] = (bf16_t)(a0[3] * l0[3] * rs);
    o8[4] = (bf16_t)(a1[0] * l1[0] * rs); o8[5] = (bf16_t)(a1[1] * l1[1] * rs);
    o8[6] = (bf16_t)(a1[2] * l1[2] * rs); o8[7] = (bf16_t)(a1[3] * l1[3] * rs);
    *(bf16x8*)&out[(size_t)row * C + tid * 8] = o8;
}

// ---------------- GEMM (2-phase + T2 source-swizzle): C = A * B^T, bf16 ----------------
// LDS slot (row, j) holds global chunk j ^ (row&7); read chunk c at slot c^(row&7).
// EPI: 0 f32 | 1 res+acc f32 | 2 gelu bf16 | 3 bf16
template<int EPI, int NSPLIT>
__global__ __launch_bounds__(256)
void gemm_bb(const bf16_t* __restrict__ A, const bf16_t* __restrict__ B,
             float* Cf, bf16_t* Cb, const float* __restrict__ res,
             int M, int N, int K, int lda, int ldb)
{
    __shared__ bf16_t As[2][128 * 64];
    __shared__ bf16_t Bs[2][128 * 64];
    if constexpr (NSPLIT > 1) {
        A  += (size_t)blockIdx.z * K;
        B  += (size_t)blockIdx.z * K;
        Cb += (size_t)blockIdx.z * (size_t)M * N;
    }
    // XCD band mapping (verified: FETCH 266->66 MB). Requires gx % 8 == 0.
    const int gx = gridDim.x;
    const int orig = blockIdx.y * gx + blockIdx.x;
    const int xcd = orig & 7;
    const int i = orig >> 3;
    const int bw = gx >> 3;
    const int m0 = (i / bw) * 128;
    const int n0 = (xcd * bw + (i % bw)) * 128;

    const int tid = threadIdx.x;
    const int lane = tid & 63, wid = tid >> 6;
    const int wr = wid >> 1, wc = wid & 1;
    const int lr = lane & 15, lg = lane >> 4;
    const int srow = lane >> 3;
    const int scol_swz = (((lane & 7) ^ (lane >> 3)) << 3);  // pre-swizzled source chunk
    f32x4 acc[4][4] = {};

    const int nt = K >> 6;
    const bf16_t* Ab = A + (size_t)m0 * lda;
    const bf16_t* Bb = B + (size_t)n0 * ldb;

    #define STAGE(bufi, kt)                                                               \
        _Pragma("unroll")                                                                 \
        for (int it = 0; it < 4; ++it) {                                                  \
            const int r = wid * 32 + it * 8;                                              \
            gload16(&Ab[(size_t)(r + srow) * lda + (kt) + scol_swz], &As[bufi][r * 64]);  \
            gload16(&Bb[(size_t)(r + srow) * ldb + (kt) + scol_swz], &Bs[bufi][r * 64]);  \
        }

    STAGE(0, 0);
    __syncthreads();
    int cur = 0;
    for (int t = 0; t < nt; ++t) {
        if (t + 1 < nt) STAGE(cur ^ 1, (t + 1) << 6);
        __builtin_amdgcn_s_setprio(1);
        #pragma unroll
        for (int kk = 0; kk < 2; ++kk) {
            bf16x8 af[4], bfr[4];
            #pragma unroll
            for (int m = 0; m < 4; ++m)
                af[m] = *(const bf16x8*)&As[cur][(wr * 64 + m * 16 + lr) * 64
                                                 + (((kk * 4 + lg) ^ (lr & 7)) << 3)];
            #pragma unroll
            for (int n = 0; n < 4; ++n)
                bfr[n] = *(const bf16x8*)&Bs[cur][(wc * 64 + n * 16 + lr) * 64
                                                  + (((kk * 4 + lg) ^ (lr & 7)) << 3)];
            #pragma unroll
            for (int m = 0; m < 4; ++m)
                #pragma unroll
                for (int n = 0; n < 4; ++n)
                    acc[m][n] = MFMA(af[m], bfr[n], acc[m][n]);
        }
        __builtin_amdgcn_s_setprio(0);
        __syncthreads();                         // one barrier/K-step, after compute
        cur ^= 1;
    }
    #undef STAGE

    // epilogue; C/D frag: col=lane&15, row=(lane>>4)*4+reg (m89-verified)
    #pragma unroll
    for (int m = 0; m < 4; ++m) {
        #pragma unroll
        for (int n = 0; n < 4; ++n) {
            const int gmb = m0 + wr * 64 + m * 16 + lg * 4;
            const int gn  = n0 + wc * 64 + n * 16 + lr;
            #pragma unroll
            for (int r = 0; r < 4; ++r) {
                const size_t off = (size_t)(gmb + r) * N + gn;
                const float v = acc[m][n][r];
                if (EPI == 0)      Cf[off] = v;
                else if (EPI == 1) Cf[off] = res[off] + v;
                else if (EPI == 2) Cb[off] = (bf16_t)(0.5f * v * (1.0f + erff(v * 0.70710678118654752f)));
                else               Cb[off] = (bf16_t)v;
            }
        }
    }
}

// ---------------- split-K reduce: out[i] = res[i] + sum_z (f32)p[z*n+i] ----------------
template<int Z>
__global__ __launch_bounds__(256)
void reduce_sk_kernel(const bf16_t* __restrict__ p, const float* __restrict__ res,
                      float* __restrict__ out, int n)
{
    for (int i = (blockIdx.x * 256 + threadIdx.x) * 8; i < n; i += gridDim.x * 256 * 8) {
        f32x4 r0 = *(const f32x4*)&res[i];
        f32x4 r1 = *(const f32x4*)&res[i + 4];
        #pragma unroll
        for (int z = 0; z < Z; ++z) {
            bf16x8 v = *(const bf16x8*)&p[(size_t)z * n + i];
            r0[0] += (float)v[0]; r0[1] += (float)v[1]; r0[2] += (float)v[2]; r0[3] += (float)v[3];
            r1[0] += (float)v[4]; r1[1] += (float)v[5]; r1[2] += (float)v[6]; r1[3] += (float)v[7];
        }
        *(f32x4*)&out[i] = r0;
        *(f32x4*)&out[i + 4] = r1;
    }
}

// ---------------- RoPE + split qkv -> q/kn/vn in [B*H][T][Dh] bf16 ----------------
__global__ __launch_bounds__(256)
void rope_split_kernel(const bf16_t* __restrict__ qkv,
                       bf16_t* __restrict__ q, bf16_t* __restrict__ kn,
                       bf16_t* __restrict__ vn, const int* __restrict__ offp)
{
    const int m = blockIdx.x;            // b*T + t
    const int b = m >> 8, t = m & 255;
    const int tid = threadIdx.x;
    const int c = tid * 8;
    const int h = c >> 7, d0 = c & 127;
    const int pos = offp[0] + t;
    bf16x8 qv = *(const bf16x8*)&qkv[(size_t)m * 6144 + c];
    bf16x8 kv = *(const bf16x8*)&qkv[(size_t)m * 6144 + 2048 + c];
    bf16x8 vv = *(const bf16x8*)&qkv[(size_t)m * 6144 + 4096 + c];
    bf16x8 qo, ko;
    #pragma unroll
    for (int p = 0; p < 4; ++p) {
        const int i = (d0 >> 1) + p;
        const float ang = (float)pos * __expf(-(float)i * 0.14391156861538527f); // ln(1e4)/64
        const float sn = sinf(ang), cs = cosf(ang);
        const float q1 = (float)qv[2 * p], q2 = (float)qv[2 * p + 1];
        const float k1 = (float)kv[2 * p], k2 = (float)kv[2 * p + 1];
        qo[2 * p]     = (bf16_t)(q1 * cs - q2 * sn);
        qo[2 * p + 1] = (bf16_t)(q1 * sn + q2 * cs);
        ko[2 * p]     = (bf16_t)(k1 * cs - k2 * sn);
        ko[2 * p + 1] = (bf16_t)(k1 * sn + k2 * cs);
    }
    const size_t oi = (((size_t)(b * 16 + h) * 256) + t) * 128 + d0;
    *(bf16x8*)&q[oi]  = qo;
    *(bf16x8*)&kn[oi] = ko;
    *(bf16x8*)&vn[oi] = vv;
}

// ---------------- Flash attention (R15 verified): block = (b,h) x 64 Q rows ----------
// 4 waves x 16 rows. Single-buffered. Vt swizzle:
// elem(d,s)=d*64+(((s>>3)^(d&7)^((d>>3)&7))<<3)+(s&7)
__global__ __launch_bounds__(256)
void attn_kernel(const bf16_t* __restrict__ qh, const bf16_t* __restrict__ kn,
                 const bf16_t* __restrict__ vn, const float* __restrict__ kcache,
                 const float* __restrict__ vcache, bf16_t* __restrict__ outp,
                 const int* __restrict__ offp)
{
    const int T = 256, Dh = 128, CAP = 2048, H = 16;
    const float scale = 0.08838834764831845f;   // 1/sqrt(128)
    __shared__ bf16_t Ks[64][136];      // [s][d], +8 pad (2-way r/w)
    __shared__ bf16_t VtL[128 * 64];    // swizzled [d][s]
    __shared__ bf16_t Pl[4][16][72];    // per-wave P relayout
    const int bh = blockIdx.x;
    const int t0 = blockIdx.y * 64;
    const int b = bh >> 4, h = bh & 15;
    const int offset = offp[0];
    const int Stot = offset + T;        // assumes offset+T <= CAP (holds here)
    const int tid = threadIdx.x, lane = tid & 63, wid = tid >> 6;
    const int lr = lane & 15, lg = lane >> 4;

    bf16x8 qf[4];
    {
        const bf16_t* qbase = qh + ((size_t)bh * T + t0 + wid * 16) * Dh;
        #pragma unroll
        for (int ks = 0; ks < 4; ++ks)
            qf[ks] = *(const bf16x8*)&qbase[lr * Dh + ks * 32 + lg * 8];
    }
    f32x4 accO[8] = {};
    float mrun[4], lrun[4];
    #pragma unroll
    for (int r = 0; r < 4; ++r) { mrun[r] = -3e38f; lrun[r] = 0.0f; }

    int smax = offset + t0 + 64; if (smax > Stot) smax = Stot;
    const int nch = (smax + 63) >> 6;

    for (int ch = 0; ch < nch; ++ch) {
        const int s0 = ch * 64;
        __syncthreads();
        #pragma unroll
        for (int it = 0; it < 4; ++it) {
            const int idx = tid + it * 256;          // 64 rows x 16 col-groups
            const int r = idx >> 4, c8 = idx & 15;
            const int s = s0 + r;
            bf16x8 kv8, vv8;
            if (s < offset) {
                const size_t base = (((size_t)b * H + h) * CAP + s) * Dh + c8 * 8;
                kv8 = cvt8(&kcache[base]);
                vv8 = cvt8(&vcache[base]);
            } else if (s < Stot) {
                const size_t base = ((size_t)bh * T + (s - offset)) * Dh + c8 * 8;
                kv8 = *(const bf16x8*)&kn[base];
                vv8 = *(const bf16x8*)&vn[base];
            } else {
                #pragma unroll
                for (int j = 0; j < 8; ++j) { kv8[j] = (bf16_t)0.0f; vv8[j] = (bf16_t)0.0f; }
            }
            *(bf16x8*)&Ks[r][c8 * 8] = kv8;
            #pragma unroll
            for (int j = 0; j < 8; ++j)
                VtL[(c8 * 8 + j) * 64 + ((((r >> 3) ^ j ^ (c8 & 7))) << 3) + (r & 7)] = vv8[j];
        }
        __syncthreads();

        f32x4 sc[4] = {};
        #pragma unroll
        for (int ks = 0; ks < 4; ++ks) {
            bf16x8 kf[4];
            #pragma unroll
            for (int n = 0; n < 4; ++n)
                kf[n] = *(const bf16x8*)&Ks[n * 16 + lr][ks * 32 + lg * 8];
            #pragma unroll
            for (int n = 0; n < 4; ++n)
                sc[n] = MFMA(qf[ks], kf[n], sc[n]);
        }

        #pragma unroll
        for (int r = 0; r < 4; ++r) {
            const int qpos = offset + t0 + wid * 16 + lg * 4 + r;
            float mx = -3e38f;
            #pragma unroll
            for (int n = 0; n < 4; ++n) {
                const int sabs = s0 + n * 16 + lr;
                float v = sc[n][r] * scale;
                v = (sabs <= qpos && sabs < Stot) ? v : -1e30f;
                sc[n][r] = v;
                mx = fmaxf(mx, v);
            }
            #pragma unroll
            for (int d = 8; d >= 1; d >>= 1) mx = fmaxf(mx, __shfl_xor(mx, d));
            const float mo = mrun[r];
            const float mn2 = fmaxf(mo, mx);
            const float al = __expf(mo - mn2);
            mrun[r] = mn2;
            lrun[r] *= al;
            #pragma unroll
            for (int df = 0; df < 8; ++df) accO[df][r] *= al;
            float rsum = 0.0f;
            #pragma unroll
            for (int n = 0; n < 4; ++n) {
                const float p = __expf(sc[n][r] - mn2);
                sc[n][r] = p;
                rsum += p;
            }
            #pragma unroll
            for (int d = 8; d >= 1; d >>= 1) rsum += __shfl_xor(rsum, d);
            lrun[r] += rsum;
            #pragma unroll
            for (int n = 0; n < 4; ++n)
                Pl[wid][lg * 4 + r][n * 16 + lr] = (bf16_t)sc[n][r];
        }
        asm volatile("s_waitcnt lgkmcnt(0)" ::: "memory");
        __builtin_amdgcn_sched_barrier(0);

        #pragma unroll
        for (int ks2 = 0; ks2 < 2; ++ks2) {
            const bf16x8 pa = *(const bf16x8*)&Pl[wid][lr][ks2 * 32 + lg * 8];
            #pragma unroll
            for (int df = 0; df < 8; ++df) {
                const int d = df * 16 + lr;
                const bf16x8 vb8 = *(const bf16x8*)
                    &VtL[d * 64 + (((ks2 * 4 + lg) ^ (d & 7) ^ ((d >> 3) & 7)) << 3)];
                accO[df] = MFMA(pa, vb8, accO[df]);
            }
        }
    }

    float rinv[4];
    #pragma unroll
    for (int r = 0; r < 4; ++r) rinv[r] = 1.0f / lrun[r];
    #pragma unroll
    for (int df = 0; df < 8; ++df) {
        #pragma unroll
        for (int r = 0; r < 4; ++r) {
            const int t = t0 + wid * 16 + lg * 4 + r;
            outp[((size_t)b * 256 + t) * 2048 + h * 128 + df * 16 + lr] =
                (bf16_t)(accO[df][r] * rinv[r]);
        }
    }
}

// ---------------- launch ----------------
extern "C" void kernel_launch(void* const* d_in, const int* in_sizes, int n_in,
                              void* d_out, int out_size, void* d_ws, size_t ws_size,
                              hipStream_t stream)
{
    const float* x    = (const float*)d_in[0];
    const float* kc   = (const float*)d_in[1];
    const float* vc   = (const float*)d_in[2];
    const float* wqkv = (const float*)d_in[3];
    const float* wo   = (const float*)d_in[4];
    const float* a1   = (const float*)d_in[5];
    const float* a2   = (const float*)d_in[6];
    const float* w1   = (const float*)d_in[7];
    const float* w2   = (const float*)d_in[8];
    const int*   offp = (const int*)d_in[9];
    float* out = (float*)d_out;

    char* ws = (char*)d_ws;
    // phase A: xn[0,8) wqkv_b[8,32) qkv[32,56)
    // phase B: q[8,16) kn[16,24) vn[24,32) wo_b[32,40) o[40,48) oprt[48,64)
    // phase C (fallback): hbuf[0,8) w1b[8,24) g_h[24,40) w2b[40,56); partials reuse [8,24)
    // phase C (big ws):   hbuf[0,8) w1b[8,40) g[40,72) w2b[72,104) partials[104,136)
    bf16_t* xn     = (bf16_t*)(ws + 0);
    bf16_t* wqkv_b = (bf16_t*)(ws + (8ull  << 20));
    bf16_t* qkv    = (bf16_t*)(ws + (32ull << 20));
    bf16_t* q      = (bf16_t*)(ws + (8ull  << 20));
    bf16_t* kn     = (bf16_t*)(ws + (16ull << 20));
    bf16_t* vn     = (bf16_t*)(ws + (24ull << 20));
    bf16_t* wo_b   = (bf16_t*)(ws + (32ull << 20));
    bf16_t* o      = (bf16_t*)(ws + (40ull << 20));
    bf16_t* oprt   = (bf16_t*)(ws + (48ull << 20));
    bf16_t* hbuf   = (bf16_t*)(ws + 0);
    const bool bigws = ws_size >= (137ull << 20);

    rmsnorm_kernel<<<2048, 256, 0, stream>>>(x, a1, xn);
    cvt_rows_kernel<<<6144, 256, 0, stream>>>(wqkv, wqkv_b, 2048, 2048);
    gemm_bb<3, 1><<<dim3(48, 16), 256, 0, stream>>>(xn, wqkv_b, nullptr, qkv, nullptr,
                                                    2048, 6144, 2048, 2048, 2048);
    rope_split_kernel<<<2048, 256, 0, stream>>>(qkv, q, kn, vn, offp);
    cvt_rows_kernel<<<2048, 256, 0, stream>>>(wo, wo_b, 2048, 2048);
    attn_kernel<<<dim3(128, 4), 256, 0, stream>>>(q, kn, vn, kc, vc, o, offp);
    gemm_bb<3, 2><<<dim3(16, 16, 2), 256, 0, stream>>>(o, wo_b, nullptr, oprt, nullptr,
                                                       2048, 2048, 1024, 2048, 2048);
    reduce_sk_kernel<2><<<2048, 256, 0, stream>>>(oprt, x, out, 2048 * 2048);
    rmsnorm_kernel<<<2048, 256, 0, stream>>>(out, a2, hbuf);

    if (bigws) {
        bf16_t* w1b = (bf16_t*)(ws + (8ull   << 20));
        bf16_t* g   = (bf16_t*)(ws + (40ull  << 20));
        bf16_t* w2b = (bf16_t*)(ws + (72ull  << 20));
        bf16_t* prt = (bf16_t*)(ws + (104ull << 20));
        cvt_rows_kernel<<<8192, 256, 0, stream>>>(w1, w1b, 2048, 2048);
        gemm_bb<2, 1><<<dim3(64, 16), 256, 0, stream>>>(hbuf, w1b, nullptr, g, nullptr,
                                                        2048, 8192, 2048, 2048, 2048);
        cvt_rows_kernel<<<2048, 256, 0, stream>>>(w2, w2b, 8192, 8192);
        gemm_bb<3, 4><<<dim3(16, 16, 4), 256, 0, stream>>>(g, w2b, nullptr, prt, nullptr,
                                                           2048, 2048, 2048, 8192, 8192);
        reduce_sk_kernel<4><<<2048, 256, 0, stream>>>(prt, out, out, 2048 * 2048);
    } else {
        bf16_t* w1b = (bf16_t*)(ws + (8ull  << 20));
        bf16_t* g_h = (bf16_t*)(ws + (24ull << 20));
        bf16_t* w2b = (bf16_t*)(ws + (40ull << 20));
        bf16_t* prt = (bf16_t*)(ws + (8ull  << 20));
        for (int hh = 0; hh < 2; ++hh) {
            cvt_rows_kernel<<<4096, 256, 0, stream>>>(w1 + (size_t)hh * 4096 * 2048, w1b, 2048, 2048);
            gemm_bb<2, 1><<<dim3(32, 16), 256, 0, stream>>>(hbuf, w1b, nullptr, g_h, nullptr,
                                                            2048, 4096, 2048, 2048, 2048);
            cvt_rows_kernel<<<2048, 256, 0, stream>>>(w2 + (size_t)hh * 4096, w2b, 4096, 8192);
            gemm_bb<3, 2><<<dim3(16, 16, 2), 256, 0, stream>>>(g_h, w2b, nullptr, prt, nullptr,
                                                               2048, 2048, 2048, 4096, 4096);
            reduce_sk_kernel<2><<<2048, 256, 0, stream>>>(prt, out, out, 2048 * 2048);
        }
    }
}

// Round 21
// 443.309 us; speedup vs baseline: 1.1484x; 1.0080x over previous
//
#include <hip/hip_runtime.h>
#include <math.h>

// StreamingTransformerLayer on MI355X (gfx950).  Round 21.
// = R15/R20 best-measured config (445-447us confirmed x2) + one zero-risk
// fusion: out-proj split-K reduce + rmsnorm#2 merged into one kernel
// (reduce block i covers exactly row i -> row-local sum-of-squares free).
// GEMM: 2-phase prefetch + T2 source-swizzle + XCD band map (all PMC-verified).
// attn: QBLK=64 grid 512, Vt both-sides XOR swizzle, plain online softmax.

typedef __bf16 bf16_t;
typedef __bf16 bf16x8 __attribute__((ext_vector_type(8)));
typedef float  f32x4  __attribute__((ext_vector_type(4)));

#define MFMA(a, b, c) __builtin_amdgcn_mfma_f32_16x16x32_bf16((a), (b), (c), 0, 0, 0)

static __device__ __forceinline__ bf16x8 cvt8(const float* __restrict__ src) {
    f32x4 f0 = *(const f32x4*)src;
    f32x4 f1 = *(const f32x4*)(src + 4);
    bf16x8 v;
    v[0] = (bf16_t)f0[0]; v[1] = (bf16_t)f0[1]; v[2] = (bf16_t)f0[2]; v[3] = (bf16_t)f0[3];
    v[4] = (bf16_t)f1[0]; v[5] = (bf16_t)f1[1]; v[6] = (bf16_t)f1[2]; v[7] = (bf16_t)f1[3];
    return v;
}

// async global->LDS, 16B per lane; lds base must be wave-uniform
static __device__ __forceinline__ void gload16(const bf16_t* g, bf16_t* lds) {
    __builtin_amdgcn_global_load_lds(
        (const __attribute__((address_space(1))) void*)g,
        (__attribute__((address_space(3))) void*)lds, 16, 0, 0);
}

// ---------------- weight convert: rows x cols, row stride (f32 -> bf16) ----------------
__global__ __launch_bounds__(256)
void cvt_rows_kernel(const float* __restrict__ src, bf16_t* __restrict__ dst,
                     int cols, int src_stride)
{
    const int row = blockIdx.x;
    const float* s = src + (size_t)row * src_stride;
    bf16_t* d = dst + (size_t)row * cols;
    for (int c = threadIdx.x * 8; c < cols; c += blockDim.x * 8)
        *(bf16x8*)&d[c] = cvt8(&s[c]);
}

// ---------------- RMSNorm: one block per row of 2048 f32, out bf16 ----------------
__global__ __launch_bounds__(256)
void rmsnorm_kernel(const float* __restrict__ x, const float* __restrict__ alpha,
                    bf16_t* __restrict__ out)
{
    const int C = 2048;
    const int row = blockIdx.x;
    const int tid = threadIdx.x;
    const float* xr = x + (size_t)row * C;
    f32x4 a0 = *(const f32x4*)&xr[tid * 8];
    f32x4 a1 = *(const f32x4*)&xr[tid * 8 + 4];
    float ss = a0[0]*a0[0] + a0[1]*a0[1] + a0[2]*a0[2] + a0[3]*a0[3]
             + a1[0]*a1[0] + a1[1]*a1[1] + a1[2]*a1[2] + a1[3]*a1[3];
    #pragma unroll
    for (int d = 32; d >= 1; d >>= 1) ss += __shfl_xor(ss, d);
    __shared__ float red[4];
    const int lane = tid & 63, wid = tid >> 6;
    if (lane == 0) red[wid] = ss;
    __syncthreads();
    const float tot = red[0] + red[1] + red[2] + red[3];
    const float rs = rsqrtf(1e-5f + tot * (1.0f / C));
    f32x4 l0 = *(const f32x4*)&alpha[tid * 8];
    f32x4 l1 = *(const f32x4*)&alpha[tid * 8 + 4];
    bf16x8 o8;
    o8[0] = (bf16_t)(a0[0] * l0[0] * rs); o8[1] = (bf16_t)(a0[1] * l0[1] * rs);
    o8[2] = (bf16_t)(a0[2] * l0[2] * rs); o8[3] = (bf16_t)(a0[3] * l0[3] * rs);
    o8[4] = (bf16_t)(a1[0] * l1[0] * rs); o8[5] = (bf16_t)(a1[1] * l1[1] * rs);
    o8[6] = (bf16_t)(a1[2] * l1[2] * rs); o8[7] = (bf16_t)(a1[3] * l1[3] * rs);
    *(bf16x8*)&out[(size_t)row * C + tid * 8] = o8;
}

// ---------------- fused: out = res + p0 + p1 ; hbuf = rmsnorm(out, alpha) ------------
// one block per row of 2048; thread covers 8 contiguous f32
__global__ __launch_bounds__(256)
void reduce_norm_kernel(const bf16_t* __restrict__ p, const float* __restrict__ res,
                        const float* __restrict__ alpha, float* __restrict__ out,
                        bf16_t* __restrict__ hbuf)
{
    const int C = 2048;
    const size_t n = (size_t)2048 * 2048;
    const int row = blockIdx.x;
    const int tid = threadIdx.x;
    const size_t i = (size_t)row * C + tid * 8;
    f32x4 r0 = *(const f32x4*)&res[i];
    f32x4 r1 = *(const f32x4*)&res[i + 4];
    bf16x8 v0 = *(const bf16x8*)&p[i];
    bf16x8 v1 = *(const bf16x8*)&p[n + i];
    r0[0] += (float)v0[0] + (float)v1[0]; r0[1] += (float)v0[1] + (float)v1[1];
    r0[2] += (float)v0[2] + (float)v1[2]; r0[3] += (float)v0[3] + (float)v1[3];
    r1[0] += (float)v0[4] + (float)v1[4]; r1[1] += (float)v0[5] + (float)v1[5];
    r1[2] += (float)v0[6] + (float)v1[6]; r1[3] += (float)v0[7] + (float)v1[7];
    *(f32x4*)&out[i]     = r0;
    *(f32x4*)&out[i + 4] = r1;
    float ss = r0[0]*r0[0] + r0[1]*r0[1] + r0[2]*r0[2] + r0[3]*r0[3]
             + r1[0]*r1[0] + r1[1]*r1[1] + r1[2]*r1[2] + r1[3]*r1[3];
    #pragma unroll
    for (int d = 32; d >= 1; d >>= 1) ss += __shfl_xor(ss, d);
    __shared__ float red[4];
    const int lane = tid & 63, wid = tid >> 6;
    if (lane == 0) red[wid] = ss;
    __syncthreads();
    const float tot = red[0] + red[1] + red[2] + red[3];
    const float rs = rsqrtf(1e-5f + tot * (1.0f / C));
    f32x4 l0 = *(const f32x4*)&alpha[tid * 8];
    f32x4 l1 = *(const f32x4*)&alpha[tid * 8 + 4];
    bf16x8 o8;
    o8[0] = (bf16_t)(r0[0] * l0[0] * rs); o8[1] = (bf16_t)(r0[1] * l0[1] * rs);
    o8[2] = (bf16_t)(r0[2] * l0[2] * rs); o8[3] = (bf16_t)(r0[3] * l0[3] * rs);
    o8[4] = (bf16_t)(r1[0] * l1[0] * rs); o8[5] = (bf16_t)(r1[1] * l1[1] * rs);
    o8[6] = (bf16_t)(r1[2] * l1[2] * rs); o8[7] = (bf16_t)(r1[3] * l1[3] * rs);
    *(bf16x8*)&hbuf[i] = o8;
}

// ---------------- GEMM (2-phase + T2 source-swizzle): C = A * B^T, bf16 ----------------
// LDS slot (row, j) holds global chunk j ^ (row&7); read chunk c at slot c^(row&7).
// EPI: 0 f32 | 1 res+acc f32 | 2 gelu bf16 | 3 bf16
template<int EPI, int NSPLIT>
__global__ __launch_bounds__(256)
void gemm_bb(const bf16_t* __restrict__ A, const bf16_t* __restrict__ B,
             float* Cf, bf16_t* Cb, const float* __restrict__ res,
             int M, int N, int K, int lda, int ldb)
{
    __shared__ bf16_t As[2][128 * 64];
    __shared__ bf16_t Bs[2][128 * 64];
    if constexpr (NSPLIT > 1) {
        A  += (size_t)blockIdx.z * K;
        B  += (size_t)blockIdx.z * K;
        Cb += (size_t)blockIdx.z * (size_t)M * N;
    }
    // XCD band mapping (verified: FETCH 266->66 MB). Requires gx % 8 == 0.
    const int gx = gridDim.x;
    const int orig = blockIdx.y * gx + blockIdx.x;
    const int xcd = orig & 7;
    const int i = orig >> 3;
    const int bw = gx >> 3;
    const int m0 = (i / bw) * 128;
    const int n0 = (xcd * bw + (i % bw)) * 128;

    const int tid = threadIdx.x;
    const int lane = tid & 63, wid = tid >> 6;
    const int wr = wid >> 1, wc = wid & 1;
    const int lr = lane & 15, lg = lane >> 4;
    const int srow = lane >> 3;
    const int scol_swz = (((lane & 7) ^ (lane >> 3)) << 3);  // pre-swizzled source chunk
    f32x4 acc[4][4] = {};

    const int nt = K >> 6;
    const bf16_t* Ab = A + (size_t)m0 * lda;
    const bf16_t* Bb = B + (size_t)n0 * ldb;

    #define STAGE(bufi, kt)                                                               \
        _Pragma("unroll")                                                                 \
        for (int it = 0; it < 4; ++it) {                                                  \
            const int r = wid * 32 + it * 8;                                              \
            gload16(&Ab[(size_t)(r + srow) * lda + (kt) + scol_swz], &As[bufi][r * 64]);  \
            gload16(&Bb[(size_t)(r + srow) * ldb + (kt) + scol_swz], &Bs[bufi][r * 64]);  \
        }

    STAGE(0, 0);
    __syncthreads();
    int cur = 0;
    for (int t = 0; t < nt; ++t) {
        if (t + 1 < nt) STAGE(cur ^ 1, (t + 1) << 6);
        __builtin_amdgcn_s_setprio(1);
        #pragma unroll
        for (int kk = 0; kk < 2; ++kk) {
            bf16x8 af[4], bfr[4];
            #pragma unroll
            for (int m = 0; m < 4; ++m)
                af[m] = *(const bf16x8*)&As[cur][(wr * 64 + m * 16 + lr) * 64
                                                 + (((kk * 4 + lg) ^ (lr & 7)) << 3)];
            #pragma unroll
            for (int n = 0; n < 4; ++n)
                bfr[n] = *(const bf16x8*)&Bs[cur][(wc * 64 + n * 16 + lr) * 64
                                                  + (((kk * 4 + lg) ^ (lr & 7)) << 3)];
            #pragma unroll
            for (int m = 0; m < 4; ++m)
                #pragma unroll
                for (int n = 0; n < 4; ++n)
                    acc[m][n] = MFMA(af[m], bfr[n], acc[m][n]);
        }
        __builtin_amdgcn_s_setprio(0);
        __syncthreads();                         // one barrier/K-step, after compute
        cur ^= 1;
    }
    #undef STAGE

    // epilogue; C/D frag: col=lane&15, row=(lane>>4)*4+reg (m89-verified)
    #pragma unroll
    for (int m = 0; m < 4; ++m) {
        #pragma unroll
        for (int n = 0; n < 4; ++n) {
            const int gmb = m0 + wr * 64 + m * 16 + lg * 4;
            const int gn  = n0 + wc * 64 + n * 16 + lr;
            #pragma unroll
            for (int r = 0; r < 4; ++r) {
                const size_t off = (size_t)(gmb + r) * N + gn;
                const float v = acc[m][n][r];
                if (EPI == 0)      Cf[off] = v;
                else if (EPI == 1) Cf[off] = res[off] + v;
                else if (EPI == 2) Cb[off] = (bf16_t)(0.5f * v * (1.0f + erff(v * 0.70710678118654752f)));
                else               Cb[off] = (bf16_t)v;
            }
        }
    }
}

// ---------------- split-K reduce: out[i] = res[i] + sum_z (f32)p[z*n+i] ----------------
template<int Z>
__global__ __launch_bounds__(256)
void reduce_sk_kernel(const bf16_t* __restrict__ p, const float* __restrict__ res,
                      float* __restrict__ out, int n)
{
    for (int i = (blockIdx.x * 256 + threadIdx.x) * 8; i < n; i += gridDim.x * 256 * 8) {
        f32x4 r0 = *(const f32x4*)&res[i];
        f32x4 r1 = *(const f32x4*)&res[i + 4];
        #pragma unroll
        for (int z = 0; z < Z; ++z) {
            bf16x8 v = *(const bf16x8*)&p[(size_t)z * n + i];
            r0[0] += (float)v[0]; r0[1] += (float)v[1]; r0[2] += (float)v[2]; r0[3] += (float)v[3];
            r1[0] += (float)v[4]; r1[1] += (float)v[5]; r1[2] += (float)v[6]; r1[3] += (float)v[7];
        }
        *(f32x4*)&out[i] = r0;
        *(f32x4*)&out[i + 4] = r1;
    }
}

// ---------------- RoPE + split qkv -> q/kn/vn in [B*H][T][Dh] bf16 ----------------
__global__ __launch_bounds__(256)
void rope_split_kernel(const bf16_t* __restrict__ qkv,
                       bf16_t* __restrict__ q, bf16_t* __restrict__ kn,
                       bf16_t* __restrict__ vn, const int* __restrict__ offp)
{
    const int m = blockIdx.x;            // b*T + t
    const int b = m >> 8, t = m & 255;
    const int tid = threadIdx.x;
    const int c = tid * 8;
    const int h = c >> 7, d0 = c & 127;
    const int pos = offp[0] + t;
    bf16x8 qv = *(const bf16x8*)&qkv[(size_t)m * 6144 + c];
    bf16x8 kv = *(const bf16x8*)&qkv[(size_t)m * 6144 + 2048 + c];
    bf16x8 vv = *(const bf16x8*)&qkv[(size_t)m * 6144 + 4096 + c];
    bf16x8 qo, ko;
    #pragma unroll
    for (int p = 0; p < 4; ++p) {
        const int i = (d0 >> 1) + p;
        const float ang = (float)pos * __expf(-(float)i * 0.14391156861538527f); // ln(1e4)/64
        const float sn = sinf(ang), cs = cosf(ang);
        const float q1 = (float)qv[2 * p], q2 = (float)qv[2 * p + 1];
        const float k1 = (float)kv[2 * p], k2 = (float)kv[2 * p + 1];
        qo[2 * p]     = (bf16_t)(q1 * cs - q2 * sn);
        qo[2 * p + 1] = (bf16_t)(q1 * sn + q2 * cs);
        ko[2 * p]     = (bf16_t)(k1 * cs - k2 * sn);
        ko[2 * p + 1] = (bf16_t)(k1 * sn + k2 * cs);
    }
    const size_t oi = (((size_t)(b * 16 + h) * 256) + t) * 128 + d0;
    *(bf16x8*)&q[oi]  = qo;
    *(bf16x8*)&kn[oi] = ko;
    *(bf16x8*)&vn[oi] = vv;
}

// ---------------- Flash attention (R15 verified): block = (b,h) x 64 Q rows ----------
// 4 waves x 16 rows. Single-buffered. Vt swizzle:
// elem(d,s)=d*64+(((s>>3)^(d&7)^((d>>3)&7))<<3)+(s&7)
__global__ __launch_bounds__(256)
void attn_kernel(const bf16_t* __restrict__ qh, const bf16_t* __restrict__ kn,
                 const bf16_t* __restrict__ vn, const float* __restrict__ kcache,
                 const float* __restrict__ vcache, bf16_t* __restrict__ outp,
                 const int* __restrict__ offp)
{
    const int T = 256, Dh = 128, CAP = 2048, H = 16;
    const float scale = 0.08838834764831845f;   // 1/sqrt(128)
    __shared__ bf16_t Ks[64][136];      // [s][d], +8 pad (2-way r/w)
    __shared__ bf16_t VtL[128 * 64];    // swizzled [d][s]
    __shared__ bf16_t Pl[4][16][72];    // per-wave P relayout
    const int bh = blockIdx.x;
    const int t0 = blockIdx.y * 64;
    const int b = bh >> 4, h = bh & 15;
    const int offset = offp[0];
    const int Stot = offset + T;        // assumes offset+T <= CAP (holds here)
    const int tid = threadIdx.x, lane = tid & 63, wid = tid >> 6;
    const int lr = lane & 15, lg = lane >> 4;

    bf16x8 qf[4];
    {
        const bf16_t* qbase = qh + ((size_t)bh * T + t0 + wid * 16) * Dh;
        #pragma unroll
        for (int ks = 0; ks < 4; ++ks)
            qf[ks] = *(const bf16x8*)&qbase[lr * Dh + ks * 32 + lg * 8];
    }
    f32x4 accO[8] = {};
    float mrun[4], lrun[4];
    #pragma unroll
    for (int r = 0; r < 4; ++r) { mrun[r] = -3e38f; lrun[r] = 0.0f; }

    int smax = offset + t0 + 64; if (smax > Stot) smax = Stot;
    const int nch = (smax + 63) >> 6;

    for (int ch = 0; ch < nch; ++ch) {
        const int s0 = ch * 64;
        __syncthreads();
        #pragma unroll
        for (int it = 0; it < 4; ++it) {
            const int idx = tid + it * 256;          // 64 rows x 16 col-groups
            const int r = idx >> 4, c8 = idx & 15;
            const int s = s0 + r;
            bf16x8 kv8, vv8;
            if (s < offset) {
                const size_t base = (((size_t)b * H + h) * CAP + s) * Dh + c8 * 8;
                kv8 = cvt8(&kcache[base]);
                vv8 = cvt8(&vcache[base]);
            } else if (s < Stot) {
                const size_t base = ((size_t)bh * T + (s - offset)) * Dh + c8 * 8;
                kv8 = *(const bf16x8*)&kn[base];
                vv8 = *(const bf16x8*)&vn[base];
            } else {
                #pragma unroll
                for (int j = 0; j < 8; ++j) { kv8[j] = (bf16_t)0.0f; vv8[j] = (bf16_t)0.0f; }
            }
            *(bf16x8*)&Ks[r][c8 * 8] = kv8;
            #pragma unroll
            for (int j = 0; j < 8; ++j)
                VtL[(c8 * 8 + j) * 64 + ((((r >> 3) ^ j ^ (c8 & 7))) << 3) + (r & 7)] = vv8[j];
        }
        __syncthreads();

        f32x4 sc[4] = {};
        #pragma unroll
        for (int ks = 0; ks < 4; ++ks) {
            bf16x8 kf[4];
            #pragma unroll
            for (int n = 0; n < 4; ++n)
                kf[n] = *(const bf16x8*)&Ks[n * 16 + lr][ks * 32 + lg * 8];
            #pragma unroll
            for (int n = 0; n < 4; ++n)
                sc[n] = MFMA(qf[ks], kf[n], sc[n]);
        }

        #pragma unroll
        for (int r = 0; r < 4; ++r) {
            const int qpos = offset + t0 + wid * 16 + lg * 4 + r;
            float mx = -3e38f;
            #pragma unroll
            for (int n = 0; n < 4; ++n) {
                const int sabs = s0 + n * 16 + lr;
                float v = sc[n][r] * scale;
                v = (sabs <= qpos && sabs < Stot) ? v : -1e30f;
                sc[n][r] = v;
                mx = fmaxf(mx, v);
            }
            #pragma unroll
            for (int d = 8; d >= 1; d >>= 1) mx = fmaxf(mx, __shfl_xor(mx, d));
            const float mo = mrun[r];
            const float mn2 = fmaxf(mo, mx);
            const float al = __expf(mo - mn2);
            mrun[r] = mn2;
            lrun[r] *= al;
            #pragma unroll
            for (int df = 0; df < 8; ++df) accO[df][r] *= al;
            float rsum = 0.0f;
            #pragma unroll
            for (int n = 0; n < 4; ++n) {
                const float p = __expf(sc[n][r] - mn2);
                sc[n][r] = p;
                rsum += p;
            }
            #pragma unroll
            for (int d = 8; d >= 1; d >>= 1) rsum += __shfl_xor(rsum, d);
            lrun[r] += rsum;
            #pragma unroll
            for (int n = 0; n < 4; ++n)
                Pl[wid][lg * 4 + r][n * 16 + lr] = (bf16_t)sc[n][r];
        }
        asm volatile("s_waitcnt lgkmcnt(0)" ::: "memory");
        __builtin_amdgcn_sched_barrier(0);

        #pragma unroll
        for (int ks2 = 0; ks2 < 2; ++ks2) {
            const bf16x8 pa = *(const bf16x8*)&Pl[wid][lr][ks2 * 32 + lg * 8];
            #pragma unroll
            for (int df = 0; df < 8; ++df) {
                const int d = df * 16 + lr;
                const bf16x8 vb8 = *(const bf16x8*)
                    &VtL[d * 64 + (((ks2 * 4 + lg) ^ (d & 7) ^ ((d >> 3) & 7)) << 3)];
                accO[df] = MFMA(pa, vb8, accO[df]);
            }
        }
    }

    float rinv[4];
    #pragma unroll
    for (int r = 0; r < 4; ++r) rinv[r] = 1.0f / lrun[r];
    #pragma unroll
    for (int df = 0; df < 8; ++df) {
        #pragma unroll
        for (int r = 0; r < 4; ++r) {
            const int t = t0 + wid * 16 + lg * 4 + r;
            outp[((size_t)b * 256 + t) * 2048 + h * 128 + df * 16 + lr] =
                (bf16_t)(accO[df][r] * rinv[r]);
        }
    }
}

// ---------------- launch ----------------
extern "C" void kernel_launch(void* const* d_in, const int* in_sizes, int n_in,
                              void* d_out, int out_size, void* d_ws, size_t ws_size,
                              hipStream_t stream)
{
    const float* x    = (const float*)d_in[0];
    const float* kc   = (const float*)d_in[1];
    const float* vc   = (const float*)d_in[2];
    const float* wqkv = (const float*)d_in[3];
    const float* wo   = (const float*)d_in[4];
    const float* a1   = (const float*)d_in[5];
    const float* a2   = (const float*)d_in[6];
    const float* w1   = (const float*)d_in[7];
    const float* w2   = (const float*)d_in[8];
    const int*   offp = (const int*)d_in[9];
    float* out = (float*)d_out;

    char* ws = (char*)d_ws;
    // phase A: xn[0,8) wqkv_b[8,32) qkv[32,56)
    // phase B: q[8,16) kn[16,24) vn[24,32) wo_b[32,40) o[40,48) oprt[48,64)
    // phase C (fallback): hbuf[0,8) w1b[8,24) g_h[24,40) w2b[40,56); partials reuse [8,24)
    // phase C (big ws):   hbuf[0,8) w1b[8,40) g[40,72) w2b[72,104) partials[104,136)
    bf16_t* xn     = (bf16_t*)(ws + 0);
    bf16_t* wqkv_b = (bf16_t*)(ws + (8ull  << 20));
    bf16_t* qkv    = (bf16_t*)(ws + (32ull << 20));
    bf16_t* q      = (bf16_t*)(ws + (8ull  << 20));
    bf16_t* kn     = (bf16_t*)(ws + (16ull << 20));
    bf16_t* vn     = (bf16_t*)(ws + (24ull << 20));
    bf16_t* wo_b   = (bf16_t*)(ws + (32ull << 20));
    bf16_t* o      = (bf16_t*)(ws + (40ull << 20));
    bf16_t* oprt   = (bf16_t*)(ws + (48ull << 20));
    bf16_t* hbuf   = (bf16_t*)(ws + 0);
    const bool bigws = ws_size >= (137ull << 20);

    rmsnorm_kernel<<<2048, 256, 0, stream>>>(x, a1, xn);
    cvt_rows_kernel<<<6144, 256, 0, stream>>>(wqkv, wqkv_b, 2048, 2048);
    gemm_bb<3, 1><<<dim3(48, 16), 256, 0, stream>>>(xn, wqkv_b, nullptr, qkv, nullptr,
                                                    2048, 6144, 2048, 2048, 2048);
    rope_split_kernel<<<2048, 256, 0, stream>>>(qkv, q, kn, vn, offp);
    cvt_rows_kernel<<<2048, 256, 0, stream>>>(wo, wo_b, 2048, 2048);
    attn_kernel<<<dim3(128, 4), 256, 0, stream>>>(q, kn, vn, kc, vc, o, offp);
    gemm_bb<3, 2><<<dim3(16, 16, 2), 256, 0, stream>>>(o, wo_b, nullptr, oprt, nullptr,
                                                       2048, 2048, 1024, 2048, 2048);
    // fused: out = x + p0 + p1 ; hbuf = rmsnorm(out, a2)
    reduce_norm_kernel<<<2048, 256, 0, stream>>>(oprt, x, a2, out, hbuf);

    if (bigws) {
        bf16_t* w1b = (bf16_t*)(ws + (8ull   << 20));
        bf16_t* g   = (bf16_t*)(ws + (40ull  << 20));
        bf16_t* w2b = (bf16_t*)(ws + (72ull  << 20));
        bf16_t* prt = (bf16_t*)(ws + (104ull << 20));
        cvt_rows_kernel<<<8192, 256, 0, stream>>>(w1, w1b, 2048, 2048);
        gemm_bb<2, 1><<<dim3(64, 16), 256, 0, stream>>>(hbuf, w1b, nullptr, g, nullptr,
                                                        2048, 8192, 2048, 2048, 2048);
        cvt_rows_kernel<<<2048, 256, 0, stream>>>(w2, w2b, 8192, 8192);
        gemm_bb<3, 4><<<dim3(16, 16, 4), 256, 0, stream>>>(g, w2b, nullptr, prt, nullptr,
                                                           2048, 2048, 2048, 8192, 8192);
        reduce_sk_kernel<4><<<2048, 256, 0, stream>>>(prt, out, out, 2048 * 2048);
    } else {
        bf16_t* w1b = (bf16_t*)(ws + (8ull  << 20));
        bf16_t* g_h = (bf16_t*)(ws + (24ull << 20));
        bf16_t* w2b = (bf16_t*)(ws + (40ull << 20));
        bf16_t* prt = (bf16_t*)(ws + (8ull  << 20));
        for (int hh = 0; hh < 2; ++hh) {
            cvt_rows_kernel<<<4096, 256, 0, stream>>>(w1 + (size_t)hh * 4096 * 2048, w1b, 2048, 2048);
            gemm_bb<2, 1><<<dim3(32, 16), 256, 0, stream>>>(hbuf, w1b, nullptr, g_h, nullptr,
                                                            2048, 4096, 2048, 2048, 2048);
            cvt_rows_kernel<<<2048, 256, 0, stream>>>(w2 + (size_t)hh * 4096, w2b, 4096, 8192);
            gemm_bb<3, 2><<<dim3(16, 16, 2), 256, 0, stream>>>(g_h, w2b, nullptr, prt, nullptr,
                                                               2048, 2048, 2048, 4096, 4096);
            reduce_sk_kernel<2><<<2048, 256, 0, stream>>>(prt, out, out, 2048 * 2048);
        }
    }
}